// Round 1
// 3092.763 us; speedup vs baseline: 1.3810x; 1.3810x over previous
//
#include <hip/hip_runtime.h>
#include <math.h>

#define Hd 512
#define Bd 64
#define Pd 32
#define Rd 4
#define Wd 64

__device__ __forceinline__ float tanh_fast(float x) {
    float e = __expf(x + x);
    return 1.f - __fdividef(2.f, 1.f + e);
}

// ---------------- build WA = [W_a | lin_w^T]  (512 x 1024) ----------------
__global__ void k_prep_wa(const float* __restrict__ Wa, const float* __restrict__ lin_w,
                          float* __restrict__ WAc) {
    __shared__ float tile[32][33];
    int bx = blockIdx.x, by = blockIdx.y;
    int lane = threadIdx.x & 31, ty = threadIdx.x >> 5;
    // copy W_a into cols 0..511 (coalesced)
    for (int k = 0; k < 32; k += 8) {
        int y = by * 32 + ty + k;
        WAc[(size_t)y * 1024 + bx * 32 + lane] = Wa[(size_t)y * Hd + bx * 32 + lane];
    }
    // transpose lin_w into cols 512..1023: WAc[h][512+c] = lin_w[c][h]
    int x = bx * 32 + lane;
    for (int k = 0; k < 32; k += 8) {
        int y = by * 32 + ty + k;
        tile[ty + k][lane] = lin_w[(size_t)y * Hd + x];
    }
    __syncthreads();
    int xo = by * 32 + lane;
    for (int k = 0; k < 32; k += 8) {
        int yo = bx * 32 + ty + k;
        WAc[(size_t)yo * 1024 + 512 + xo] = tile[lane][ty + k];
    }
}

// ---------------- Wctx[b,p,k] = sum_h ctx[b,p,h] * Wc[h,k] ----------------
__global__ void k_wctx(const float* __restrict__ ctx_pbh, const float* __restrict__ Wc,
                       float* __restrict__ Wctx) {
    __shared__ float As[16][Hd];
    int r0 = blockIdx.x * 16;
    int tid = threadIdx.x;
    for (int rr = 0; rr < 16; ++rr) {
        int bp = r0 + rr;
        int b = bp >> 5, p = bp & 31;
        const float* src = ctx_pbh + ((size_t)p * Bd + b) * Hd;
        for (int h = tid; h < Hd; h += 256) As[rr][h] = src[h];
    }
    __syncthreads();
    int c0 = tid, c1 = tid + 256;
    float acc0[16], acc1[16];
    #pragma unroll
    for (int rr = 0; rr < 16; ++rr) { acc0[rr] = 0.f; acc1[rr] = 0.f; }
    for (int h = 0; h < Hd; ++h) {
        float w0 = Wc[(size_t)h * Hd + c0], w1 = Wc[(size_t)h * Hd + c1];
        #pragma unroll
        for (int rr = 0; rr < 16; ++rr) {
            float a = As[rr][h];
            acc0[rr] += a * w0;
            acc1[rr] += a * w1;
        }
    }
    for (int rr = 0; rr < 16; ++rr) {
        Wctx[(size_t)(r0 + rr) * Hd + c0] = acc0[rr];
        Wctx[(size_t)(r0 + rr) * Hd + c1] = acc1[rr];
    }
}

// ---------------- rw[t*256+row][k] = sum_h resp[r,t,b,h] * Wt[h,k] ----------------
__global__ __launch_bounds__(256) void k_rw(const float* __restrict__ resp,
                                            const float* __restrict__ Wt,
                                            float* __restrict__ rw) {
    __shared__ float As[16][Hd];
    int gr0 = blockIdx.x * 16;
    int tid = threadIdx.x;
    for (int rr = 0; rr < 16; ++rr) {
        int gr = gr0 + rr;
        int t = gr >> 8, row = gr & 255;
        int r = row >> 6, bb = row & 63;
        const float* src = resp + (((size_t)(r * Wd + t)) * Bd + bb) * Hd;
        for (int h = tid; h < Hd; h += 256) As[rr][h] = src[h];
    }
    __syncthreads();
    int c0 = tid, c1 = tid + 256;
    float acc0[16], acc1[16];
    #pragma unroll
    for (int rr = 0; rr < 16; ++rr) { acc0[rr] = 0.f; acc1[rr] = 0.f; }
    for (int h = 0; h < Hd; ++h) {
        float w0 = Wt[(size_t)h * Hd + c0], w1 = Wt[(size_t)h * Hd + c1];
        #pragma unroll
        for (int rr = 0; rr < 16; ++rr) {
            float a = As[rr][h];
            acc0[rr] += a * w0;
            acc1[rr] += a * w1;
        }
    }
    for (int rr = 0; rr < 16; ++rr) {
        rw[(size_t)(gr0 + rr) * Hd + c0] = acc0[rr];
        rw[(size_t)(gr0 + rr) * Hd + c1] = acc1[rr];
    }
}

// ---------------- persistent scan: 64 blocks (one per b), 1024 threads ----------------
// 16 waves/block = 4 waves/SIMD (was 1) to hide L2 latency of the WA stream.
// GEMM is split-K x2: groups g=0/1 each cover 256 of the 512 h, partials
// combined via LDS (sPart), with the rw add folded into the reduction.
__global__ __launch_bounds__(1024, 4) void k_scan(
    const float* __restrict__ ctx,      // (P,B,H)
    const float* __restrict__ rw,       // (W*256, H)
    const float* __restrict__ WA,       // (H, 1024)
    const float* __restrict__ Wctx,     // (B*P, H)
    const float* __restrict__ walpha,   // (H)
    const float* __restrict__ hidden,   // (R,B,H)
    const float* __restrict__ lin_p,    // (H,H) row-major, row = out col
    const float* __restrict__ lin_x,    // (H,H)
    float* __restrict__ out_resp,       // (R,B,H)
    float* __restrict__ out_alpha)      // (R,W,B,P)
{
    __shared__ float sAtten[Rd][Hd];          //  8 KB
    __shared__ float sW[Rd][2 * Hd];          // 16 KB
    __shared__ float sPart[2][Rd][2 * Hd];    // 32 KB (split-K partials; reused for hidden in epilogue)
    __shared__ float sWal[Hd];                //  2 KB
    __shared__ float sScore[Rd][Pd];
    __shared__ float sAlpha[Rd][Pd];

    const int b = blockIdx.x;
    const int tid = threadIdx.x;

    for (int i = tid; i < Rd * Hd; i += 1024) ((float*)sAtten)[i] = 0.f;
    if (tid < Hd) sWal[tid] = walpha[tid];
    __syncthreads();

    // --- phase A identity: h-half g, column pair c2 ---
    const int g  = tid >> 9;                   // 0..1
    const int c2 = (tid & 511) * 2;            // 0..1022
    const int h0 = g * 256;
    const float* __restrict__ wabase = WA + (size_t)h0 * 1024 + c2;

    // --- reduce identity: row rr_, 4-col group c4 ---
    const int rr_ = tid >> 8;                  // 0..3
    const int c4  = (tid & 255) * 4;           // 0..1020

    // --- phase B identity: 32 threads per p ---
    const int pB  = tid >> 5;                  // 0..31
    const int hcB = tid & 31;
    const float* __restrict__ wrow = Wctx + ((size_t)(b * Pd + pB)) * Hd;

    // --- phase D identity ---
    const int rD = tid >> 8;                   // 0..3
    const int hD = (tid & 255) * 2;            // 0..510

    for (int t = 0; t < Wd; ++t) {
        // prefetch rw for the reduce phase (latency hides under the GEMM)
        float4 rv = make_float4(0.f, 0.f, 0.f, 0.f);
        if (c4 < Hd)
            rv = *(const float4*)&rw[((size_t)t * 256 + rr_ * 64 + b) * Hd + c4];

        // ---- A: partial fused GEMM  [w | lw](c2,c2+1) over h in [h0,h0+256) ----
        float2 acc0 = make_float2(0.f, 0.f), acc1 = acc0, acc2 = acc0, acc3 = acc0;
        #pragma unroll 2
        for (int hh = 0; hh < 256; hh += 4) {
            const int h = h0 + hh;
            const float* q = wabase + (size_t)hh * 1024;
            float2 w0 = *(const float2*)(q);
            float2 w1 = *(const float2*)(q + 1024);
            float2 w2 = *(const float2*)(q + 2048);
            float2 w3 = *(const float2*)(q + 3072);
            float4 a0 = *(const float4*)&sAtten[0][h];
            float4 a1 = *(const float4*)&sAtten[1][h];
            float4 a2 = *(const float4*)&sAtten[2][h];
            float4 a3 = *(const float4*)&sAtten[3][h];
            acc0.x += a0.x*w0.x + a0.y*w1.x + a0.z*w2.x + a0.w*w3.x;
            acc0.y += a0.x*w0.y + a0.y*w1.y + a0.z*w2.y + a0.w*w3.y;
            acc1.x += a1.x*w0.x + a1.y*w1.x + a1.z*w2.x + a1.w*w3.x;
            acc1.y += a1.x*w0.y + a1.y*w1.y + a1.z*w2.y + a1.w*w3.y;
            acc2.x += a2.x*w0.x + a2.y*w1.x + a2.z*w2.x + a2.w*w3.x;
            acc2.y += a2.x*w0.y + a2.y*w1.y + a2.z*w2.y + a2.w*w3.y;
            acc3.x += a3.x*w0.x + a3.y*w1.x + a3.z*w2.x + a3.w*w3.x;
            acc3.y += a3.x*w0.y + a3.y*w1.y + a3.z*w2.y + a3.w*w3.y;
        }
        *(float2*)&sPart[g][0][c2] = acc0;
        *(float2*)&sPart[g][1][c2] = acc1;
        *(float2*)&sPart[g][2][c2] = acc2;
        *(float2*)&sPart[g][3][c2] = acc3;
        __syncthreads();

        // ---- reduce split-K partials + rw → sW ----
        {
            float4 p0 = *(const float4*)&sPart[0][rr_][c4];
            float4 p1 = *(const float4*)&sPart[1][rr_][c4];
            float4 o = make_float4(p0.x + p1.x + rv.x, p0.y + p1.y + rv.y,
                                   p0.z + p1.z + rv.z, p0.w + p1.w + rv.w);
            *(float4*)&sW[rr_][c4] = o;
        }
        __syncthreads();

        // ---- B: tanh-score: score[r][p] = sum_h tanh(Wctx[b,p,h]+w[r,h])*walpha[h] ----
        {
            float sc0 = 0.f, sc1 = 0.f, sc2 = 0.f, sc3 = 0.f;
            #pragma unroll
            for (int k = 0; k < 4; ++k) {
                int h4 = k * 128 + hcB * 4;     // interleaved: coalesced + bank-clean
                float4 wc  = *(const float4*)&wrow[h4];
                float4 wal = *(const float4*)&sWal[h4];
                float4 v0 = *(const float4*)&sW[0][h4];
                float4 v1 = *(const float4*)&sW[1][h4];
                float4 v2 = *(const float4*)&sW[2][h4];
                float4 v3 = *(const float4*)&sW[3][h4];
                sc0 += tanh_fast(wc.x+v0.x)*wal.x + tanh_fast(wc.y+v0.y)*wal.y
                     + tanh_fast(wc.z+v0.z)*wal.z + tanh_fast(wc.w+v0.w)*wal.w;
                sc1 += tanh_fast(wc.x+v1.x)*wal.x + tanh_fast(wc.y+v1.y)*wal.y
                     + tanh_fast(wc.z+v1.z)*wal.z + tanh_fast(wc.w+v1.w)*wal.w;
                sc2 += tanh_fast(wc.x+v2.x)*wal.x + tanh_fast(wc.y+v2.y)*wal.y
                     + tanh_fast(wc.z+v2.z)*wal.z + tanh_fast(wc.w+v2.w)*wal.w;
                sc3 += tanh_fast(wc.x+v3.x)*wal.x + tanh_fast(wc.y+v3.y)*wal.y
                     + tanh_fast(wc.z+v3.z)*wal.z + tanh_fast(wc.w+v3.w)*wal.w;
            }
            #pragma unroll
            for (int off = 16; off; off >>= 1) {
                sc0 += __shfl_down(sc0, off, 32);
                sc1 += __shfl_down(sc1, off, 32);
                sc2 += __shfl_down(sc2, off, 32);
                sc3 += __shfl_down(sc3, off, 32);
            }
            if (hcB == 0) { sScore[0][pB] = sc0; sScore[1][pB] = sc1;
                            sScore[2][pB] = sc2; sScore[3][pB] = sc3; }
        }
        __syncthreads();

        // ---- C: softmax over p (threads 0..127: 4 rows x 32 lanes) ----
        if (tid < 128) {
            int r = tid >> 5, pp = tid & 31;
            float s = sScore[r][pp];
            float m = s;
            #pragma unroll
            for (int off = 16; off; off >>= 1) m = fmaxf(m, __shfl_xor(m, off, 32));
            float e = __expf(s - m);
            float sum = e;
            #pragma unroll
            for (int off = 16; off; off >>= 1) sum += __shfl_xor(sum, off, 32);
            float al = e * __fdividef(1.f, sum);
            sAlpha[r][pp] = al;
            out_alpha[(((size_t)r * Wd + t) * Bd + b) * Pd + pp] = al;
        }
        __syncthreads();

        // ---- D: atten update: atten = sum_p alpha*ctx + tanh(lw) ----
        {
            float a0 = 0.f, a1 = 0.f;
            const float* cp = ctx + (size_t)b * Hd + hD;
            #pragma unroll 8
            for (int pp = 0; pp < Pd; ++pp) {
                float al = sAlpha[rD][pp];
                float2 cv = *(const float2*)(cp + (size_t)pp * Bd * Hd);
                a0 += al * cv.x;
                a1 += al * cv.y;
            }
            a0 += tanh_fast(sW[rD][Hd + hD]);
            a1 += tanh_fast(sW[rD][Hd + hD + 1]);
            *(float2*)&sAtten[rD][hD] = make_float2(a0, a1);
        }
        __syncthreads();
    }

    // ---- epilogue: resp_c = tanh(atten@lin_p^T + hidden@lin_x^T) ----
    for (int i = tid; i < Rd * Hd; i += 1024) {
        int r = i >> 9, h = i & 511;
        ((float*)sPart)[i] = hidden[((size_t)r * Bd + b) * Hd + h];
    }
    __syncthreads();
    {
        const int r2 = tid >> 9;               // 0..1 -> rows {2r2, 2r2+1}
        const int c  = tid & 511;
        const int ra = r2 * 2, rb = ra + 1;
        const float* __restrict__ lp = lin_p + (size_t)c * Hd;
        const float* __restrict__ lx = lin_x + (size_t)c * Hd;
        const float* __restrict__ hA = (const float*)sPart + (size_t)ra * Hd;
        const float* __restrict__ hB = (const float*)sPart + (size_t)rb * Hd;
        float fa = 0.f, fb = 0.f;
        #pragma unroll 2
        for (int h = 0; h < Hd; h += 4) {
            float4 lpv = *(const float4*)(lp + h);
            float4 lxv = *(const float4*)(lx + h);
            float4 aa  = *(const float4*)&sAtten[ra][h];
            float4 ab  = *(const float4*)&sAtten[rb][h];
            float4 ha  = *(const float4*)(hA + h);
            float4 hb  = *(const float4*)(hB + h);
            fa += aa.x*lpv.x + aa.y*lpv.y + aa.z*lpv.z + aa.w*lpv.w
                + ha.x*lxv.x + ha.y*lxv.y + ha.z*lxv.z + ha.w*lxv.w;
            fb += ab.x*lpv.x + ab.y*lpv.y + ab.z*lpv.z + ab.w*lpv.w
                + hb.x*lxv.x + hb.y*lxv.y + hb.z*lxv.z + hb.w*lxv.w;
        }
        out_resp[((size_t)ra * Bd + b) * Hd + c] = tanh_fast(fa);
        out_resp[((size_t)rb * Bd + b) * Hd + c] = tanh_fast(fb);
    }
}

extern "C" void kernel_launch(void* const* d_in, const int* in_sizes, int n_in,
                              void* d_out, int out_size, void* d_ws, size_t ws_size,
                              hipStream_t stream) {
    const float* ctx    = (const float*)d_in[0];  // (P,B,H)
    const float* resp   = (const float*)d_in[1];  // (R,W,B,H)
    const float* hidden = (const float*)d_in[2];  // (R,B,H)
    const float* Wc     = (const float*)d_in[3];
    const float* Wt     = (const float*)d_in[4];
    const float* Wa     = (const float*)d_in[5];
    const float* Walpha = (const float*)d_in[6];  // (H,1)
    const float* lin_w  = (const float*)d_in[7];
    const float* lin_p  = (const float*)d_in[8];
    const float* lin_x  = (const float*)d_in[9];

    float* out = (float*)d_out;
    float* resp_c_out = out;                       // R*B*H = 131072
    float* alpha_out  = out + Rd * Bd * Hd;        // R*W*B*P = 524288

    float* ws   = (float*)d_ws;
    float* WAc  = ws;                    //   524288 floats (512x1024)
    float* Wctx = WAc + 524288;          //  1048576
    float* rwb  = Wctx + 1048576;        //  8388608 (64*256*512)

    dim3 g16(16, 16);
    k_prep_wa<<<g16, 256, 0, stream>>>(Wa, lin_w, WAc);
    k_wctx<<<128, 256, 0, stream>>>(ctx, Wc, Wctx);
    k_rw<<<1024, 256, 0, stream>>>(resp, Wt, rwb);
    k_scan<<<64, 1024, 0, stream>>>(ctx, rwb, WAc, Wctx, Walpha, hidden,
                                    lin_p, lin_x, resp_c_out, alpha_out);
}